// Round 1
// 21383.571 us; speedup vs baseline: 1.8072x; 1.8072x over previous
//
#include <hip/hip_runtime.h>

// ---------------------------------------------------------------------------
// LSTMDecoder: B=16 S=256 V=32000 H=1024 E=512 DQ=512
// Strategy:
//   - precompute hidden_VQ, hs_proj, gate bases (gbase, h0g) AND
//     M = hidden_VQ @ W_ih[:,512:1536]^T  so the recurrence never needs
//     "weighted" explicitly:  weighted@Wihw^T == sum_s attn[b,s]*M[b,s,:]
//   - persistent 255-step kernel, 256 blocks x 512 threads, THREE grid
//     syncs/step through a hierarchical (16x16) barrier with per-group
//     release lines (the old single-line barrier was ~30us/sync from
//     256 RMWs + 255 pollers on one cacheline)
//   - attn recorded per step; weighted_t rebuilt post-scan by one batched
//     MFMA GEMM into Ah; logits = ONE big fp16 MFMA GEMM vs pred_W
// ---------------------------------------------------------------------------

typedef _Float16 half8 __attribute__((ext_vector_type(8)));
typedef _Float16 half4 __attribute__((ext_vector_type(4)));
typedef float    f32x4 __attribute__((ext_vector_type(4)));

__device__ __forceinline__ float fast_tanh(float x) {
  x = fminf(fmaxf(x, -15.f), 15.f);
  const float e = __expf(2.f * x);
  return (e - 1.f) * __builtin_amdgcn_rcpf(e + 1.f);
}
__device__ __forceinline__ float fast_sigm(float x) {
  x = fminf(fmaxf(x, -30.f), 30.f);
  return __builtin_amdgcn_rcpf(1.f + __expf(-x));
}

// ---- hierarchical grid barrier (monotonic counters; zeroed by k_init) -----
// layout (unsigned words): grp[g] at g*64 (g=0..15), glob at 1024,
//                          rel[g] at 1088+g*64 (g=0..15). 2112 words total.
// 256 blocks = 16 groups x 16 members (group = blockIdx & 15).
__device__ __forceinline__ void grid_sync(unsigned* bar, unsigned step) {
  __syncthreads();
  if (threadIdx.x == 0) {
    const unsigned g = blockIdx.x & 15u;
    unsigned old = __hip_atomic_fetch_add(bar + g * 64, 1u,
                                          __ATOMIC_ACQ_REL, __HIP_MEMORY_SCOPE_AGENT);
    if (old == step * 16u - 1u) {               // last arriver of this group
      unsigned go = __hip_atomic_fetch_add(bar + 1024, 1u,
                                           __ATOMIC_ACQ_REL, __HIP_MEMORY_SCOPE_AGENT);
      if (go == step * 16u - 1u) {              // last group -> release all
        __threadfence();                        // one agent-scope release fence
        #pragma unroll
        for (int i = 0; i < 16; ++i)
          __hip_atomic_store(bar + 1088 + i * 64, step,
                             __ATOMIC_RELAXED, __HIP_MEMORY_SCOPE_AGENT);
      }
    }
    // only ~16 pollers per release line -> no same-line queueing collapse
    while (__hip_atomic_load(bar + 1088 + g * 64,
                             __ATOMIC_ACQUIRE, __HIP_MEMORY_SCOPE_AGENT) < step)
      __builtin_amdgcn_s_sleep(2);
  }
  __syncthreads();
}

// ---- fp32 -> fp16 strided convert: dst[n*Kd+k] = src[n*Ks+off+k] ----------
__global__ __launch_bounds__(256) void k_cvt(_Float16* __restrict__ dst,
                                             const float* __restrict__ src,
                                             int Kd, int Ks, int off, int total4) {
  int i = blockIdx.x * 256 + threadIdx.x;
  if (i >= total4) return;
  int i4 = i << 2;
  int n = i4 / Kd;
  int k = i4 - n * Kd;
  f32x4 s = *(const f32x4*)(src + (size_t)n * Ks + off + k);
  half4 d;
  d[0] = (_Float16)s[0]; d[1] = (_Float16)s[1];
  d[2] = (_Float16)s[2]; d[3] = (_Float16)s[3];
  *(half4*)(dst + (size_t)n * Kd + k) = d;
}

// ---- embedding gather: Ae[(t*16+b)][e] = embed_W[inputs[b,t]][e] ----------
__global__ __launch_bounds__(256) void k_gather(_Float16* __restrict__ Ae,
                                                const float* __restrict__ embedW,
                                                const int* __restrict__ inputs) {
  int i = blockIdx.x * 256 + threadIdx.x;   // over 4096*512/4
  if (i >= 524288) return;
  int i4 = i << 2;
  int r = i4 >> 9;
  int e = i4 & 511;
  int t = r >> 4, b = r & 15;
  half4 d;
  if (t < 255) {
    int tok = inputs[b * 256 + t];
    f32x4 s = *(const f32x4*)(embedW + (size_t)tok * 512 + e);
    d[0] = (_Float16)s[0]; d[1] = (_Float16)s[1];
    d[2] = (_Float16)s[2]; d[3] = (_Float16)s[3];
  } else {
    d[0] = d[1] = d[2] = d[3] = (_Float16)0.f;
  }
  *(half4*)(Ae + (size_t)r * 512 + e) = d;
}

// ---- init: c0/h0, bsum, Ah tail zero, out[:,0,:]=0, barrier words=0,
//      attn_rec row t=255 = 0 ---------------------------------------------
__global__ __launch_bounds__(256) void k_init(const _Float16* __restrict__ hvq16,
                                              float* cbuf, _Float16* h16, _Float16* h016,
                                              const float* __restrict__ bih,
                                              const float* __restrict__ bhh, float* bsum,
                                              _Float16* Ah, float* out,
                                              _Float16* attn_rec, unsigned* bar) {
  int gi = blockIdx.x * 256 + threadIdx.x;
  if (gi < 16384) {
    int b = gi >> 10, k = gi & 1023;
    float cv = (float)hvq16[(size_t)((b << 8) + 255) * 1024 + k];
    cbuf[gi] = cv;
    float hn = fast_tanh(cv);
    _Float16 hf = (_Float16)hn;
    h16[gi] = hf;
    h016[gi] = hf;
  } else if (gi < 65536) {          // h016 pad rows 16..63 -> 0
    h016[gi] = (_Float16)0.f;
  } else if (gi < 69632) {          // bsum = b_ih + b_hh
    int j = gi - 65536;
    bsum[j] = bih[j] + bhh[j];
  } else if (gi < 102400) {         // Ah rows for t=255 -> 0
    Ah[(size_t)4080 * 2048 + (gi - 69632)] = (_Float16)0.f;
  } else if (gi < 614400) {         // out[:, 0, :] = 0
    int idx = gi - 102400;
    int b = idx / 32000, v = idx - b * 32000;
    out[(size_t)b * 8192000 + v] = 0.f;
  } else if (gi < 616512) {         // barrier words (2112) -> 0
    bar[gi - 614400] = 0u;
  } else if (gi < 620608) {         // attn_rec[:, t=255, :] -> 0
    int idx = gi - 616512;
    int b = idx >> 8, s = idx & 255;
    attn_rec[((size_t)(b << 8) + 255) * 256 + s] = (_Float16)0.f;
  }
}

// ---- transpose hidden_VQ16 [16][256][1024] -> hvT16 [16][1024][256] -------
__global__ __launch_bounds__(256) void k_t(const _Float16* __restrict__ in,
                                           _Float16* __restrict__ out) {
  __shared__ _Float16 tile[32][34];
  int b = blockIdx.z, s0 = blockIdx.y << 5, h0 = blockIdx.x << 5;
  int row = threadIdx.x >> 5;     // 0..7
  int col = threadIdx.x & 31;
  #pragma unroll
  for (int rr = 0; rr < 32; rr += 8)
    tile[row + rr][col] = in[(size_t)((b << 8) + s0 + row + rr) * 1024 + h0 + col];
  __syncthreads();
  #pragma unroll
  for (int rr = 0; rr < 32; rr += 8)
    out[(size_t)((b << 10) + h0 + row + rr) * 256 + s0 + col] = tile[col][row + rr];
}

// ---- generic fp16 MFMA GEMM: C[m][n] = sum_k A[m][k]*B[n][k] (+bias[n]) ---
// 64x64 block tile, 4 waves each 16(M)x64(N), 16x16x32 f16 MFMA.
// EPI: 0 = fp16 store, 1 = fp32 store, 2 = scatter to out[b, t+1, :],
//      3 = scatter into Ah[(row*16+z)*2048 + 1024 + col] (weighted rebuild)
// sA/sB: per-blockIdx.z batch strides (elements).
template <int EPI, int BIAS>
__global__ __launch_bounds__(256) void k_mfma(const _Float16* __restrict__ A,
                                              const _Float16* __restrict__ Bm,
                                              void* __restrict__ Cout,
                                              const float* __restrict__ bias,
                                              const int N, const int K,
                                              const size_t sA, const size_t sB) {
  A  += (size_t)blockIdx.z * sA;
  Bm += (size_t)blockIdx.z * sB;
  __shared__ _Float16 As[64][40];
  __shared__ _Float16 Bs[64][40];
  const int tid  = threadIdx.x;
  const int lane = tid & 63;
  const int wv   = tid >> 6;
  const int quad = lane >> 4;
  const int q8   = quad << 3;
  const int l15  = lane & 15;
  const int m0   = blockIdx.y << 6;
  const int n0   = blockIdx.x << 6;
  const int lr   = tid >> 2;
  const int lc   = (tid & 3) << 3;
  f32x4 acc[4] = {{0.f,0.f,0.f,0.f},{0.f,0.f,0.f,0.f},{0.f,0.f,0.f,0.f},{0.f,0.f,0.f,0.f}};
  for (int kt = 0; kt < K; kt += 32) {
    *(half8*)&As[lr][lc] = *(const half8*)&A[(size_t)(m0 + lr) * K + kt + lc];
    *(half8*)&Bs[lr][lc] = *(const half8*)&Bm[(size_t)(n0 + lr) * K + kt + lc];
    __syncthreads();
    const half8 av = *(const half8*)&As[(wv << 4) + l15][q8];
    #pragma unroll
    for (int nt = 0; nt < 4; ++nt) {
      const half8 bv = *(const half8*)&Bs[(nt << 4) + l15][q8];
      acc[nt] = __builtin_amdgcn_mfma_f32_16x16x32_f16(av, bv, acc[nt], 0, 0, 0);
    }
    __syncthreads();
  }
  #pragma unroll
  for (int nt = 0; nt < 4; ++nt) {
    #pragma unroll
    for (int r = 0; r < 4; ++r) {
      const int row = m0 + (wv << 4) + (quad << 2) + r;
      const int col = n0 + (nt << 4) + l15;
      float v = acc[nt][r];
      if (BIAS) v += bias[col];
      if (EPI == 0) {
        ((_Float16*)Cout)[(size_t)row * N + col] = (_Float16)v;
      } else if (EPI == 1) {
        ((float*)Cout)[(size_t)row * N + col] = v;
      } else if (EPI == 2) {
        const int tt = row >> 4, bb = row & 15;
        if (tt < 255)
          ((float*)Cout)[(size_t)bb * 8192000 + (size_t)(tt + 1) * 32000 + col] = v;
      } else {
        if (row < 255)
          ((_Float16*)Cout)[(size_t)(row * 16 + blockIdx.z) * 2048 + 1024 + col] =
              (_Float16)v;
      }
    }
  }
}

// ---- persistent sequential scan (255 steps, 3 grid syncs/step) ------------
// grid MUST be 256 blocks x 512 threads (all co-resident on 256 CUs).
__global__ __launch_bounds__(512) void k_seq(
    const _Float16* __restrict__ hsp16,    // [4096][1024] hs_proj
    const _Float16* __restrict__ gbase16,  // [4096][4096]
    const float*    __restrict__ h0g,      // [64][4096] (rows 0..15 used)
    const _Float16* __restrict__ Wh16,     // [1024][1024] attn_W[:, :H]
    const _Float16* __restrict__ Whh16,    // [4096][1024]
    const _Float16* __restrict__ M16,      // [4096][4096] = hvq @ Wihw^T
    const float*    __restrict__ vvec,     // [1024]
    _Float16* h16, float* cbuf, float* hWh, float* gatesh,
    float* score, _Float16* attn_rec, _Float16* Ah, unsigned* bar) {
  const int tid  = threadIdx.x;
  const int lane = tid & 63;
  const int wv   = tid >> 6;               // 0..7
  const int bx   = blockIdx.x;             // 0..255
  const int gw   = (bx << 3) | wv;         // global wave 0..2047
  const int quad = lane >> 4;
  const int q8   = quad << 3;
  const int l15  = lane & 15;
  unsigned step = 0;

  __shared__ float red[8][64][4];          // MFMA partials (P1 & P3 reuse)
  __shared__ float attn_s[256];            // softmax result (P3)

  // fixed P3 role: this block owns batch p3_b, hidden units [p3_hc, p3_hc+64)
  const int p3_b  = bx >> 4;
  const int p3_hc = (bx & 15) << 6;

  #pragma unroll 1
  for (int t = 0; t < 255; ++t) {
    // ==== P1: gatesh = h @ Whh^T (waves 0-3, K-split 256) ;
    //          hWh    = h @ Wh^T  (waves 4-7, blocks 0..63) ================
    {
      const bool doWh = (wv >= 4);
      const int  kb   = (wv & 3) << 8;
      const int  n0   = bx << 4;
      if (!doWh || bx < 64) {
        const _Float16* ar = h16 + l15 * 1024 + kb + q8;
        const _Float16* br = (doWh ? Wh16 : Whh16) + (size_t)(n0 + l15) * 1024 + kb + q8;
        f32x4 acc = {0.f, 0.f, 0.f, 0.f};
        #pragma unroll
        for (int kk = 0; kk < 256; kk += 32)
          acc = __builtin_amdgcn_mfma_f32_16x16x32_f16(
              *(const half8*)(ar + kk), *(const half8*)(br + kk), acc, 0, 0, 0);
        #pragma unroll
        for (int r = 0; r < 4; ++r) red[wv][lane][r] = acc[r];
      }
      __syncthreads();
      if (tid < 256) {                      // reduce 4 K-chunks -> gatesh
        const int b = tid >> 4, nl = tid & 15;
        const int ll = ((b >> 2) << 4) + nl, rr = b & 3;
        gatesh[b * 4096 + n0 + nl] =
            red[0][ll][rr] + red[1][ll][rr] + red[2][ll][rr] + red[3][ll][rr];
      } else if (bx < 64) {                 // reduce -> hWh
        const int t2 = tid - 256;
        const int b = t2 >> 4, nl = t2 & 15;
        const int ll = ((b >> 2) << 4) + nl, rr = b & 3;
        hWh[b * 1024 + n0 + nl] =
            red[4][ll][rr] + red[5][ll][rr] + red[6][ll][rr] + red[7][ll][rr];
      }
    }
    ++step; grid_sync(bar, step);

    // ==== P2: score[b,s] = sum_j v[j]*tanh(hWh[b,j] + hs_proj[b,s,j]) =====
    #pragma unroll
    for (int rep = 0; rep < 2; ++rep) {
      const int tk = gw + (rep << 11);      // 0..4095
      const int b  = tk >> 8;
      const _Float16* hp = hsp16 + (size_t)tk * 1024;
      const float* hwb = hWh + b * 1024;
      float acc = 0.f;
      #pragma unroll
      for (int g2 = 0; g2 < 2; ++g2) {
        const int j0 = g2 * 512 + lane * 8;
        half8 hv = *(const half8*)(hp + j0);
        f32x4 w0 = *(const f32x4*)(hwb + j0);
        f32x4 w1 = *(const f32x4*)(hwb + j0 + 4);
        f32x4 v0 = *(const f32x4*)(vvec + j0);
        f32x4 v1 = *(const f32x4*)(vvec + j0 + 4);
        #pragma unroll
        for (int e = 0; e < 4; ++e) {
          acc += v0[e] * fast_tanh(w0[e] + (float)hv[e]);
          acc += v1[e] * fast_tanh(w1[e] + (float)hv[e + 4]);
        }
      }
      #pragma unroll
      for (int m = 32; m; m >>= 1) acc += __shfl_xor(acc, m, 64);
      if (lane == 0) score[tk] = acc;
    }
    ++step; grid_sync(bar, step);

    // ==== P3: softmax (replicated) + gates via M + pointwise ==============
    {
      if (wv == 0) {                        // softmax for p3_b -> attn_s
        const float* sc = score + (p3_b << 8);
        float s0 = sc[lane], s1 = sc[lane + 64], s2 = sc[lane + 128], s3 = sc[lane + 192];
        float mx = fmaxf(fmaxf(s0, s1), fmaxf(s2, s3));
        #pragma unroll
        for (int m = 32; m; m >>= 1) mx = fmaxf(mx, __shfl_xor(mx, m, 64));
        float e0 = __expf(s0 - mx), e1 = __expf(s1 - mx);
        float e2 = __expf(s2 - mx), e3 = __expf(s3 - mx);
        float z = e0 + e1 + e2 + e3;
        #pragma unroll
        for (int m = 32; m; m >>= 1) z += __shfl_xor(z, m, 64);
        const float inv = __builtin_amdgcn_rcpf(z);
        e0 *= inv; e1 *= inv; e2 *= inv; e3 *= inv;
        attn_s[lane] = e0; attn_s[lane + 64] = e1;
        attn_s[lane + 128] = e2; attn_s[lane + 192] = e3;
        if (p3_hc == 0) {                   // record attn for post-scan GEMM
          _Float16* ap = attn_rec + ((size_t)(p3_b << 8) + t) * 256;
          ap[lane] = (_Float16)e0; ap[lane + 64] = (_Float16)e1;
          ap[lane + 128] = (_Float16)e2; ap[lane + 192] = (_Float16)e3;
        }
      }
      __syncthreads();
      // gates partial: wave w owns s-chunk [w*32, w*32+32); lane covers
      // gate p = lane>>4, 4 units (lane&15)*4.. via coalesced half4 loads
      {
        const int p   = lane >> 4;
        const int nl4 = (lane & 15) << 2;
        const _Float16* mp = M16 + ((size_t)(p3_b << 8) + (wv << 5)) * 4096 +
                             (p << 10) + p3_hc + nl4;
        f32x4 acc = {0.f, 0.f, 0.f, 0.f};
        #pragma unroll 8
        for (int s = 0; s < 32; ++s) {
          const float a = attn_s[(wv << 5) + s];
          half4 mv = *(const half4*)(mp + (size_t)s * 4096);
          acc[0] += a * (float)mv[0];
          acc[1] += a * (float)mv[1];
          acc[2] += a * (float)mv[2];
          acc[3] += a * (float)mv[3];
        }
        #pragma unroll
        for (int r = 0; r < 4; ++r) red[wv][lane][r] = acc[r];
      }
      __syncthreads();
      if (tid < 64) {                       // pointwise LSTM for 64 units
        const int u = p3_hc + tid;
        const size_t grow = (size_t)(t * 16 + p3_b) * 4096;
        float g4[4];
        #pragma unroll
        for (int p = 0; p < 4; ++p) {
          const int li = (p << 4) + (tid >> 2);
          const int rr = tid & 3;
          const int n  = (p << 10) + u;
          float s8 = red[0][li][rr] + red[1][li][rr] + red[2][li][rr] + red[3][li][rr] +
                     red[4][li][rr] + red[5][li][rr] + red[6][li][rr] + red[7][li][rr];
          g4[p] = s8 + (float)gbase16[grow + n] + h0g[p3_b * 4096 + n] +
                  gatesh[p3_b * 4096 + n];
        }
        const float ig = fast_sigm(g4[0]);
        const float fg = fast_sigm(g4[1]);
        const float gg = fast_tanh(g4[2]);
        const float og = fast_sigm(g4[3]);
        const int ci = (p3_b << 10) + u;
        const float cn2 = fg * cbuf[ci] + ig * gg;
        cbuf[ci] = cn2;
        const float hn = og * fast_tanh(cn2);
        const _Float16 hf = (_Float16)hn;
        h16[ci] = hf;
        Ah[(size_t)(t * 16 + p3_b) * 2048 + u] = hf;
      }
    }
    ++step; grid_sync(bar, step);
  }
}

// ---------------------------------------------------------------------------
extern "C" void kernel_launch(void* const* d_in, const int* in_sizes, int n_in,
                              void* d_out, int out_size, void* d_ws, size_t ws_size,
                              hipStream_t stream) {
  const int*   inputs  = (const int*)  d_in[0];
  const float* VQembed = (const float*)d_in[1];
  const float* embedW  = (const float*)d_in[2];
  const float* transW  = (const float*)d_in[3];
  const float* attnW   = (const float*)d_in[4];
  const float* attnb   = (const float*)d_in[5];
  const float* vvec    = (const float*)d_in[6];
  const float* Wih     = (const float*)d_in[7];
  const float* Whh     = (const float*)d_in[8];
  const float* bih     = (const float*)d_in[9];
  const float* bhh     = (const float*)d_in[10];
  const float* predW   = (const float*)d_in[11];
  float* out = (float*)d_out;

  char* w = (char*)d_ws;
  size_t off = 0;
  auto take = [&](size_t bytes) -> char* {
    char* p = w + off;
    off = (off + bytes + 255) & ~(size_t)255;
    return p;
  };
  // ~282 MB total workspace
  _Float16* hvq16   = (_Float16*)take(4096ULL * 1024 * 2);   // hidden_VQ fp16
  _Float16* hsp16   = (_Float16*)take(4096ULL * 1024 * 2);   // hs_proj fp16
  _Float16* hvT16   = (_Float16*)take(16ULL * 1024 * 256 * 2);
  _Float16* gbase16 = (_Float16*)take(4096ULL * 4096 * 2);
  float*    h0g     = (float*)   take(64ULL * 4096 * 4);
  _Float16* Ah      = (_Float16*)take(4096ULL * 2048 * 2);   // [h_t, weighted_t]
  _Float16* pw16    = (_Float16*)take(32000ULL * 2048 * 2);
  _Float16* M16     = (_Float16*)take(4096ULL * 4096 * 2);   // hvq @ Wihw^T
  _Float16* attnrec = (_Float16*)take(16ULL * 256 * 256 * 2);// attn record [b][t][s]
  _Float16* vq16    = (_Float16*)take(4096ULL * 512 * 2);
  _Float16* ae16    = (_Float16*)take(4096ULL * 512 * 2);
  _Float16* tw16    = (_Float16*)take(1024ULL * 512 * 2);
  _Float16* wk16    = (_Float16*)take(1024ULL * 1024 * 2);
  _Float16* wh16    = (_Float16*)take(1024ULL * 1024 * 2);
  _Float16* whh16   = (_Float16*)take(4096ULL * 1024 * 2);
  _Float16* wihe16  = (_Float16*)take(4096ULL * 512 * 2);
  _Float16* wihw16  = (_Float16*)take(4096ULL * 1024 * 2);
  _Float16* wihh016 = (_Float16*)take(4096ULL * 1024 * 2);
  float*    bsum    = (float*)   take(4096ULL * 4);
  float*    cbuf    = (float*)   take(16ULL * 1024 * 4);
  _Float16* h16     = (_Float16*)take(16ULL * 1024 * 2);
  _Float16* h016    = (_Float16*)take(64ULL * 1024 * 2);
  float*    hWh     = (float*)   take(16ULL * 1024 * 4);
  float*    gatesh  = (float*)   take(16ULL * 4096 * 4);
  float*    score   = (float*)   take(4096ULL * 4);
  unsigned* bar     = (unsigned*)take(16384);
  (void)ws_size; (void)in_sizes; (void)n_in; (void)out_size;

  auto cvt = [&](_Float16* dst, const float* src, int N, int Kd, int Ks, int o) {
    int total4 = (N * Kd) >> 2;
    k_cvt<<<(total4 + 255) / 256, 256, 0, stream>>>(dst, src, Kd, Ks, o, total4);
  };
  // weight/activation converts (one-time)
  cvt(vq16,    VQembed, 4096,  512,  512,  0);
  cvt(tw16,    transW,  1024,  512,  512,  0);
  cvt(wk16,    attnW,   1024, 1024, 2048, 1024);
  cvt(wh16,    attnW,   1024, 1024, 2048, 0);
  cvt(whh16,   Whh,     4096, 1024, 1024, 0);
  cvt(wihe16,  Wih,     4096,  512, 2560, 0);
  cvt(wihw16,  Wih,     4096, 1024, 2560, 512);
  cvt(wihh016, Wih,     4096, 1024, 2560, 1536);
  cvt(pw16,    predW,  32000, 2048, 2048, 0);
  k_gather<<<2048, 256, 0, stream>>>(ae16, embedW, inputs);

  // hidden_VQ = VQembed @ trans_W^T  (M=4096 N=1024 K=512)
  k_mfma<0, 0><<<dim3(16, 64), 256, 0, stream>>>(vq16, tw16, hvq16, nullptr, 1024, 512, 0, 0);
  // init state, biases, zeros, barrier words, attn_rec pad row
  k_init<<<2425, 256, 0, stream>>>(hvq16, cbuf, h16, h016, bih, bhh, bsum, Ah, out,
                                   attnrec, bar);
  // transpose for post-scan weighted GEMM (B operand = hvT[b][h][s])
  k_t<<<dim3(32, 8, 16), 256, 0, stream>>>(hvq16, hvT16);
  // hs_proj = hidden_VQ @ attn_W[:,H:]^T + attn_b  (M=4096 N=1024 K=1024)
  k_mfma<0, 1><<<dim3(16, 64), 256, 0, stream>>>(hvq16, wk16, hsp16, attnb, 1024, 1024, 0, 0);
  // gbase = we @ W_ih[:, :E]^T  (M=4096 N=4096 K=512)
  k_mfma<0, 0><<<dim3(64, 64), 256, 0, stream>>>(ae16, wihe16, gbase16, nullptr, 4096, 512, 0, 0);
  // h0g = h0 @ W_ih[:, E+H:]^T + (b_ih + b_hh)  (M=64 N=4096 K=1024)
  k_mfma<1, 1><<<dim3(64, 1), 256, 0, stream>>>(h016, wihh016, h0g, bsum, 4096, 1024, 0, 0);
  // M = hidden_VQ @ W_ih[:,512:1536]^T  (M=4096 N=4096 K=1024)
  k_mfma<0, 0><<<dim3(64, 64), 256, 0, stream>>>(hvq16, wihw16, M16, nullptr, 4096, 1024, 0, 0);

  // sequential 255-step scan (3 grid syncs/step, hierarchical barrier)
  k_seq<<<256, 512, 0, stream>>>(hsp16, gbase16, h0g, wh16, whh16, M16, vvec,
                                 h16, cbuf, hWh, gatesh, score, attnrec, Ah, bar);

  // weighted_t rebuild: per b, C[t][h] = sum_s attn[b,t,s]*hvT[b][h][s]
  // scattered into Ah[(t*16+b)][1024+h]  (M=256 N=1024 K=256, 16 batches)
  k_mfma<3, 0><<<dim3(16, 4, 16), 256, 0, stream>>>(attnrec, hvT16, Ah, nullptr,
                                                    1024, 256, 65536, 262144);

  // logits: [h_t, weighted_t] @ pred_W^T -> out[b, t+1, :]  (M=4096 N=32000 K=2048)
  k_mfma<2, 0><<<dim3(500, 64), 256, 0, stream>>>(Ah, pw16, out, nullptr, 32000, 2048, 0, 0);
}